// Round 5
// baseline (174.933 us; speedup 1.0000x reference)
//
#include <hip/hip_runtime.h>
#include <hip/hip_bf16.h>

// ---- problem constants ----
#define NN 25000
#define PP 100000
#define TT 4
#define DD 128
#define LEAKY 0.001f

#define PB 32          // propers per chunk (8 waves x 4 propers)
#define ROWS 128       // PB * TT rows of the MLP per chunk

typedef __bf16 bf16;
typedef __bf16 bf16x8 __attribute__((ext_vector_type(8)));
typedef float  f32x4  __attribute__((ext_vector_type(4)));
typedef float  f32x2  __attribute__((ext_vector_type(2)));

// ---- workspace layout (bytes) ----
#define OFF_W0SW  0u                    // 128 chunks * 1KB (fragment order)
#define OFF_W1SW  131072u               // 32 chunks * 1KB   (W1|W2|W3 contiguous)
#define OFF_W2SW  163840u               // 32 chunks * 1KB
#define OFF_W3SW  196608u               // 4 chunks * 1KB
#define OFF_WTB   200704u               // Wt[t][j] = t*W0[512]+b0, 4*128 bf16
#define OFF_W5B   201728u               // W0 rows 513..515 as bf16
#define OFF_E     202496u               // 4 tables [NN][128] bf16 = 25,600,000 B
#define WS_END    25802496u

// prep work partition (thread counts)
#define PR_W0SW  8192
#define PR_W1SW  2048
#define PR_W2SW  2048
#define PR_W3SW  256
#define PR_WTB   64
#define PR_W5B   48
#define PR_COPY4 75000
#define PR_TOTAL (PR_W0SW + PR_W1SW + PR_W2SW + PR_W3SW + PR_WTB + PR_W5B + PR_COPY4)

#define LGKM0() asm volatile("s_waitcnt lgkmcnt(0)" ::: "memory")

__device__ __forceinline__ void gload_lds16(const void* g, void* l) {
    __builtin_amdgcn_global_load_lds(
        (const __attribute__((address_space(1))) void*)g,
        (__attribute__((address_space(3))) void*)l, 16, 0, 0);
}

__global__ __launch_bounds__(256) void prep_kernel(
    const float* __restrict__ W0, const float* __restrict__ W1,
    const float* __restrict__ W2, const float* __restrict__ W3,
    const float* __restrict__ answer, const float* __restrict__ tvec,
    const float* __restrict__ b0,
    bf16* __restrict__ W0sw, bf16* __restrict__ W1sw, bf16* __restrict__ W2sw,
    bf16* __restrict__ W3sw, bf16* __restrict__ WtB, bf16* __restrict__ W5B,
    float* __restrict__ out)
{
    int idx = blockIdx.x * 256 + threadIdx.x;
    if (idx < PR_W0SW) {                 // one chunk-lane per thread: 8 elems
        int lane = idx & 63, c = idx >> 6;
        int fr = lane & 15, quad = lane >> 4;
        int kc = c & 15, iwv = c >> 4;
        bf16 v[8];
        #pragma unroll
        for (int j = 0; j < 8; ++j)
            v[j] = (bf16)W0[(kc * 32 + quad * 8 + j) * 128 + iwv * 16 + fr];
        *(bf16x8*)(W0sw + c * 512 + lane * 8) = *(const bf16x8*)v;
        return;
    }
    idx -= PR_W0SW;
    if (idx < PR_W1SW) {
        int lane = idx & 63, c = idx >> 6;
        int fr = lane & 15, quad = lane >> 4;
        int kc = c & 3, nt = c >> 2;
        bf16 v[8];
        #pragma unroll
        for (int j = 0; j < 8; ++j)
            v[j] = (bf16)W1[(kc * 32 + quad * 8 + j) * 128 + nt * 16 + fr];
        *(bf16x8*)(W1sw + c * 512 + lane * 8) = *(const bf16x8*)v;
        return;
    }
    idx -= PR_W1SW;
    if (idx < PR_W2SW) {
        int lane = idx & 63, c = idx >> 6;
        int fr = lane & 15, quad = lane >> 4;
        int kc = c & 3, nt = c >> 2;
        bf16 v[8];
        #pragma unroll
        for (int j = 0; j < 8; ++j)
            v[j] = (bf16)W2[(kc * 32 + quad * 8 + j) * 128 + nt * 16 + fr];
        *(bf16x8*)(W2sw + c * 512 + lane * 8) = *(const bf16x8*)v;
        return;
    }
    idx -= PR_W2SW;
    if (idx < PR_W3SW) {
        int lane = idx & 63, kc = idx >> 6;
        int fr = lane & 15, quad = lane >> 4;
        bf16 v[8];
        #pragma unroll
        for (int j = 0; j < 8; ++j)
            v[j] = (fr < 2) ? (bf16)W3[(kc * 32 + quad * 8 + j) * 2 + fr] : (bf16)0.0f;
        *(bf16x8*)(W3sw + kc * 512 + lane * 8) = *(const bf16x8*)v;
        return;
    }
    idx -= PR_W3SW;
    if (idx < PR_WTB) {                 // Wt[t][j] = tvec[t]*W0[512][j] + b0[j]
        int t = idx >> 4, s = idx & 15;
        float tv = tvec[t];
        bf16 v[8];
        #pragma unroll
        for (int j = 0; j < 8; ++j)
            v[j] = (bf16)(tv * W0[512 * 128 + s * 8 + j] + b0[s * 8 + j]);
        *(bf16x8*)(WtB + t * 128 + s * 8) = *(const bf16x8*)v;
        return;
    }
    idx -= PR_WTB;
    if (idx < PR_W5B) {                 // W0 rows 513,514,515 -> bf16
        int r = idx >> 4, s = idx & 15;
        bf16 v[8];
        #pragma unroll
        for (int j = 0; j < 8; ++j)
            v[j] = (bf16)W0[(513 + r) * 128 + s * 8 + j];
        *(bf16x8*)(W5B + r * 128 + s * 8) = *(const bf16x8*)v;
        return;
    }
    idx -= PR_W5B;
    if (idx < PR_COPY4) { ((float4*)out)[idx] = ((const float4*)answer)[idx]; }
}

// E_i[n][j] = sum_k enc[n][k]*W0[i*128+k][j]. 256-thread / 64-row blocks.
__global__ __launch_bounds__(256) void prep_e_kernel(
    const float* __restrict__ encoded, const bf16* __restrict__ W0sw,
    bf16* __restrict__ E)
{
    __shared__ bf16 sA[64][136];
    __shared__ bf16 sT[64][40];
    const int tid = threadIdx.x;
    const int row0 = (blockIdx.x >> 2) * 64;
    const int ntb  = blockIdx.x & 3;
    for (int c = tid; c < 2048; c += 256) {      // 64 rows x 32 float4
        int row = c >> 5, seg = c & 31;
        int rr = row0 + row; if (rr >= NN) rr = NN - 1;
        float4 v = *(const float4*)(encoded + (size_t)rr * 128 + seg * 4);
        bf16 pk[4] = {(bf16)v.x, (bf16)v.y, (bf16)v.z, (bf16)v.w};
        *(uint2*)(&sA[row][seg * 4]) = *(const uint2*)pk;
    }
    __syncthreads();                             // sA staged (cross-wave)
    const int wv = tid >> 6, lane = tid & 63;
    const int fr = lane & 15, quad = lane >> 4;
    const bf16* aBase = &sA[wv * 16 + fr][quad * 8];
    bf16x8 aFv[4];
    #pragma unroll
    for (int kcc = 0; kcc < 4; ++kcc) aFv[kcc] = *(const bf16x8*)(aBase + kcc * 32);
    const int orow = tid >> 2, oseg = tid & 3;
    #pragma unroll
    for (int i = 0; i < 4; ++i) {
        #pragma unroll
        for (int ntl = 0; ntl < 2; ++ntl) {
            int nt = ntb * 2 + ntl;
            f32x4 acc = {0.f, 0.f, 0.f, 0.f};
            #pragma unroll
            for (int kcc = 0; kcc < 4; ++kcc) {
                bf16x8 bF = *(const bf16x8*)(W0sw + ((size_t)nt * 16 + i * 4 + kcc) * 512 + lane * 8);
                acc = __builtin_amdgcn_mfma_f32_16x16x32_bf16(aFv[kcc], bF, acc, 0, 0, 0);
            }
            #pragma unroll
            for (int reg = 0; reg < 4; ++reg)
                sT[wv * 16 + quad * 4 + reg][ntl * 16 + fr] = (bf16)acc[reg];
        }
        LGKM0();                                 // own sT writes visible to own wave
        bf16x8 ev = *(const bf16x8*)(&sT[orow][oseg * 8]);
        LGKM0();                                 // reads retired before next i's overwrite
        if (row0 + orow < NN)
            *(bf16x8*)(E + ((size_t)i * NN + row0 + orow) * 128 + ntb * 32 + oseg * 8) = ev;
    }
}

// ---------------------------------------------------------------------------
// Main kernel, R19: PERSISTENT blocks, all weights LDS-resident, zero
// steady-state barriers.
//
// R18 post-mortem: VALUBusy dropped 55->42% with dur pinned at 74 us; all
// pipes <50%. The wall is the per-chunk serial chain: 2 weight-staging
// phases + 3 barrier drains per 32-proper chunk at 2 blocks/CU (plus 400 MB
// of L2 weight re-staging). Fix: 256 blocks (1/CU, 107.7 KB LDS), stage
// W1|W2|W3 (contiguous 68 KB) ONCE, one __syncthreads, then loop chunks with
// NO barriers (sH/sScr/sNd wave-private; same-wave DS is in-order — R18
// validated). Next chunk's propers issue at iteration top; dependent E-gather
// + coords issue after h0 and fly across the dense phase. Invariant Wt/W5B/
// bias loads hoisted out of the loop. launch_bounds(512,2): 256-VGPR budget.
// ---------------------------------------------------------------------------
__global__ __launch_bounds__(512, 2) void main_kernel(
    const float* __restrict__ coords, const int* __restrict__ propers,
    const float* __restrict__ b1, const float* __restrict__ b2,
    const float* __restrict__ b3,
    const bf16* __restrict__ E, const bf16* __restrict__ W1sw,
    const bf16* __restrict__ W2sw, const bf16* __restrict__ W3sw,
    const bf16* __restrict__ WtB, const bf16* __restrict__ W5B,
    float* __restrict__ out)
{
    __shared__ __align__(16) bf16 sH[8][16][136];   // per-wave activation tile
    __shared__ __align__(16) bf16 sW[34816];        // 68KB: W1 | W2 | W3 frags
    __shared__ float sScr[8][16][6];                // [0..2]=dh, [3..4]=delta
    __shared__ int   sNd[8][8];                     // per-wave {n0,n3} x 4 propers

    const int tid  = threadIdx.x;
    const int wv   = tid >> 6, lane = tid & 63;
    const int fr   = lane & 15, quad = lane >> 4;

    // ---- one-time weight stage: 68 wave-instrs over 8 waves ----
    for (int i = wv; i < 68; i += 8)
        gload_lds16((const char*)W1sw + (size_t)i * 1024 + lane * 16,
                    (char*)sW + i * 1024);

    // ---- loop-invariant preloads (biases, W5B rows, Wt rows) ----
    float b1r[8], b2r[8];
    #pragma unroll
    for (int i = 0; i < 8; ++i) {
        b1r[i] = b1[i * 16 + fr];
        b2r[i] = b2[i * 16 + fr];
    }
    float b3r = (fr < 2) ? b3[fr] : 0.0f;
    bf16x8 w3v = *(const bf16x8*)(W5B + 0 * 128 + fr * 8);
    bf16x8 w4v = *(const bf16x8*)(W5B + 1 * 128 + fr * 8);
    bf16x8 w5v = *(const bf16x8*)(W5B + 2 * 128 + fr * 8);
    bf16x8 wtv[4];
    #pragma unroll
    for (int t = 0; t < 4; ++t) wtv[t] = *(const bf16x8*)(WtB + t * 128 + fr * 8);
    f32x2 w3f2[4], w4f2[4], w5f2[4];
    #pragma unroll
    for (int j = 0; j < 4; ++j) {
        w3f2[j] = (f32x2){ (float)w3v[2*j], (float)w3v[2*j+1] };
        w4f2[j] = (f32x2){ (float)w4v[2*j], (float)w4v[2*j+1] };
        w5f2[j] = (f32x2){ (float)w5v[2*j], (float)w5v[2*j+1] };
    }

    __syncthreads();   // weights resident — the ONLY barrier in this kernel

    const int nChunks = PP / PB;          // 3125
    const int stride  = gridDim.x;        // 256
    int chunk = blockIdx.x;

    // ---- prologue prefetch for the first chunk ----
    int4 pv; bf16x8 e0, e1, e2, e3; float cc[12];
    {
        int pw = chunk * PB + wv * 4;
        pv = *(const int4*)(propers + (size_t)(pw + quad) * 4);
        e0 = *(const bf16x8*)(E + ((size_t)0 * NN + pv.x) * 128 + fr * 8);
        e1 = *(const bf16x8*)(E + ((size_t)1 * NN + pv.y) * 128 + fr * 8);
        e2 = *(const bf16x8*)(E + ((size_t)2 * NN + pv.z) * 128 + fr * 8);
        e3 = *(const bf16x8*)(E + ((size_t)3 * NN + pv.w) * 128 + fr * 8);
        if (lane < 16) {
            int4 pg = *(const int4*)(propers + (size_t)(pw + (lane >> 2)) * 4);
            int t = lane & 3;
            const float* q0 = coords + (size_t)pg.x * 12 + t * 3;
            const float* q1 = coords + (size_t)pg.y * 12 + t * 3;
            const float* q2 = coords + (size_t)pg.z * 12 + t * 3;
            const float* q3 = coords + (size_t)pg.w * 12 + t * 3;
            cc[0]=q0[0]; cc[1]=q0[1]; cc[2]=q0[2];
            cc[3]=q1[0]; cc[4]=q1[1]; cc[5]=q1[2];
            cc[6]=q2[0]; cc[7]=q2[1]; cc[8]=q2[2];
            cc[9]=q3[0]; cc[10]=q3[1]; cc[11]=q3[2];
        }
    }

    while (true) {
        const int next = chunk + stride;
        const bool more = next < nChunks;

        // ---- stage A for next chunk: propers loads (static addresses) ----
        int4 pvn, pgn;
        if (more) {
            int pwn = next * PB + wv * 4;
            pvn = *(const int4*)(propers + (size_t)(pwn + quad) * 4);
            if (lane < 16)
                pgn = *(const int4*)(propers + (size_t)(pwn + (lane >> 2)) * 4);
        }

        if (fr == 0) { sNd[wv][quad * 2] = pv.x; sNd[wv][quad * 2 + 1] = pv.w; }

        // ---- geometry (pure VALU from prefetched cc) ----
        float snl = 0.f, csl = 1.f, dll = 0.f;
        if (lane < 16) {
            float u1x = cc[3]-cc[0], u1y = cc[4]-cc[1], u1z = cc[5]-cc[2];
            float u2x = cc[6]-cc[3], u2y = cc[7]-cc[4], u2z = cc[8]-cc[5];
            float u3x = cc[9]-cc[6], u3y = cc[10]-cc[7], u3z = cc[11]-cc[8];
            float ax = u1y*u2z - u1z*u2y, ay = u1z*u2x - u1x*u2z, az = u1x*u2y - u1y*u2x;
            float bx = u2y*u3z - u2z*u3y, by = u2z*u3x - u2x*u3z, bz = u2x*u3y - u2y*u3x;
            float u2n = sqrtf(u2x*u2x + u2y*u2y + u2z*u2z);
            float num = u2n * (u1x*bx + u1y*by + u1z*bz);
            float den = ax*bx + ay*by + az*bz;
            float hyp = sqrtf(num*num + den*den);
            if (hyp > 1e-30f) { float ih = 1.0f / hyp; snl = num * ih; csl = den * ih; }
            else { snl = 0.0f; csl = 1.0f; }
            float drx = cc[0]-cc[9], dry = cc[1]-cc[10], drz = cc[2]-cc[11];
            dll = sqrtf(fmaxf(drx*drx + dry*dry + drz*drz, 1e-12f));
            float il = 1.0f / dll;
            sScr[wv][lane][0] = drx * il;
            sScr[wv][lane][1] = dry * il;
            sScr[wv][lane][2] = drz * il;
        }

        // ---- h0 = leaky(g + Wt[t] + sn*w513 + cs*w514 + dl*w515) -> sH[wv] ----
        {
            f32x2 g2[4];
            #pragma unroll
            for (int j = 0; j < 4; ++j)
                g2[j] = (f32x2){
                    (float)e0[2*j]   + (float)e1[2*j]   + (float)e2[2*j]   + (float)e3[2*j],
                    (float)e0[2*j+1] + (float)e1[2*j+1] + (float)e2[2*j+1] + (float)e3[2*j+1] };
            #pragma unroll
            for (int t = 0; t < 4; ++t) {
                int r = quad * 4 + t;                         // wave-relative row
                float sn = __shfl(snl, r), cs = __shfl(csl, r), dl = __shfl(dll, r);
                f32x2 sn2 = {sn, sn}, cs2 = {cs, cs}, dl2 = {dl, dl};
                bf16 hv[8];
                #pragma unroll
                for (int j = 0; j < 4; ++j) {
                    f32x2 v = g2[j] + (f32x2){ (float)wtv[t][2*j], (float)wtv[t][2*j+1] };
                    v = sn2 * w3f2[j] + v;
                    v = cs2 * w4f2[j] + v;
                    v = dl2 * w5f2[j] + v;
                    f32x2 lv = v * LEAKY;
                    v.x = fmaxf(v.x, lv.x);
                    v.y = fmaxf(v.y, lv.y);
                    hv[2*j]   = (bf16)v.x;
                    hv[2*j+1] = (bf16)v.y;
                }
                *(bf16x8*)(&sH[wv][r][fr * 8]) = *(const bf16x8*)hv;
            }
        }

        // ---- stage B for next chunk: E gather + coords (fly across dense) ----
        bf16x8 e0n, e1n, e2n, e3n; float ccn[12];
        if (more) {
            e0n = *(const bf16x8*)(E + ((size_t)0 * NN + pvn.x) * 128 + fr * 8);
            e1n = *(const bf16x8*)(E + ((size_t)1 * NN + pvn.y) * 128 + fr * 8);
            e2n = *(const bf16x8*)(E + ((size_t)2 * NN + pvn.z) * 128 + fr * 8);
            e3n = *(const bf16x8*)(E + ((size_t)3 * NN + pvn.w) * 128 + fr * 8);
            if (lane < 16) {
                int t2 = lane & 3;
                const float* q0 = coords + (size_t)pgn.x * 12 + t2 * 3;
                const float* q1 = coords + (size_t)pgn.y * 12 + t2 * 3;
                const float* q2 = coords + (size_t)pgn.z * 12 + t2 * 3;
                const float* q3 = coords + (size_t)pgn.w * 12 + t2 * 3;
                ccn[0]=q0[0]; ccn[1]=q0[1]; ccn[2]=q0[2];
                ccn[3]=q1[0]; ccn[4]=q1[1]; ccn[5]=q1[2];
                ccn[6]=q2[0]; ccn[7]=q2[1]; ccn[8]=q2[2];
                ccn[9]=q3[0]; ccn[10]=q3[1]; ccn[11]=q3[2];
            }
        }

        // ---- dense layers: A-frags from own sH, B-frags from resident sW ----
#define DENSE_LAYER(OFFW, BR)                                                   \
    {                                                                           \
        bf16x8 aF[4];                                                           \
        const bf16* aRow = &sH[wv][fr][quad * 8];                               \
        _Pragma("unroll")                                                       \
        for (int kc = 0; kc < 4; ++kc)                                          \
            aF[kc] = *(const bf16x8*)(aRow + kc * 32);                          \
        _Pragma("unroll")                                                       \
        for (int hh = 0; hh < 2; ++hh) {                                        \
            f32x4 acc[4];                                                       \
            _Pragma("unroll")                                                   \
            for (int nt = 0; nt < 4; ++nt) acc[nt] = (f32x4){0.f,0.f,0.f,0.f};  \
            __builtin_amdgcn_s_setprio(1);                                      \
            _Pragma("unroll")                                                   \
            for (int kc = 0; kc < 4; ++kc) {                                    \
                _Pragma("unroll")                                               \
                for (int nt = 0; nt < 4; ++nt) {                                \
                    bf16x8 bF = *(const bf16x8*)(sW + OFFW +                    \
                        ((hh * 4 + nt) * 4 + kc) * 512 + lane * 8);             \
                    acc[nt] = __builtin_amdgcn_mfma_f32_16x16x32_bf16(          \
                        aF[kc], bF, acc[nt], 0, 0, 0);                          \
                }                                                               \
            }                                                                   \
            __builtin_amdgcn_s_setprio(0);                                      \
            _Pragma("unroll")                                                   \
            for (int nt = 0; nt < 4; ++nt) {                                    \
                int j = (hh * 4 + nt) * 16 + fr;                                \
                f32x4 v = acc[nt] + BR[hh * 4 + nt];                            \
                f32x4 lv = v * LEAKY;                                           \
                v.x = fmaxf(v.x, lv.x); v.y = fmaxf(v.y, lv.y);                 \
                v.z = fmaxf(v.z, lv.z); v.w = fmaxf(v.w, lv.w);                 \
                _Pragma("unroll")                                               \
                for (int reg = 0; reg < 4; ++reg)                               \
                    sH[wv][quad * 4 + reg][j] = (bf16)v[reg];                   \
            }                                                                   \
        }                                                                       \
    }

        DENSE_LAYER(0, b1r)          // h1 = leaky(h0 @ W1 + b1), in place
        DENSE_LAYER(16384, b2r)      // h2 = leaky(h1 @ W2 + b2), in place

        // ---- delta = h2 @ W3 + b3 (zero-padded); W3 frags at sW+32768 ----
        {
            bf16x8 aF[4];
            const bf16* aRow = &sH[wv][fr][quad * 8];
            #pragma unroll
            for (int kc = 0; kc < 4; ++kc)
                aF[kc] = *(const bf16x8*)(aRow + kc * 32);
            f32x4 dacc = {0.f, 0.f, 0.f, 0.f};
            __builtin_amdgcn_s_setprio(1);
            #pragma unroll
            for (int kc = 0; kc < 4; ++kc) {
                bf16x8 bF = *(const bf16x8*)(sW + 32768 + kc * 512 + lane * 8);
                dacc = __builtin_amdgcn_mfma_f32_16x16x32_bf16(aF[kc], bF, dacc, 0, 0, 0);
            }
            __builtin_amdgcn_s_setprio(0);
            if (fr < 2) {
                #pragma unroll
                for (int reg = 0; reg < 4; ++reg)
                    sScr[wv][quad * 4 + reg][3 + fr] = dacc[reg] + b3r;
            }
        }

        // ---- scatter-add: 16 rows x 6 comps, lane-constant mapping ----
        {
            int row = lane & 15;
            int comp = lane >> 4;                      // 0..3
            int side = (comp == 3) ? 1 : 0;
            int ax = side ? 0 : comp;
            int node = sNd[wv][(row >> 2) * 2 + side];
            float dval = (side ? 0.5f : -0.5f) * sScr[wv][row][3 + side];
            atomicAdd(out + (size_t)node * 12 + (row & 3) * 3 + ax, dval * sScr[wv][row][ax]);
            if (lane < 32) {                           // comps 4,5: side 1, ax 1,2
                int ax2 = 1 + comp;
                int node2 = sNd[wv][(row >> 2) * 2 + 1];
                float dval2 = 0.5f * sScr[wv][row][4];
                atomicAdd(out + (size_t)node2 * 12 + (row & 3) * 3 + ax2, dval2 * sScr[wv][row][ax2]);
            }
        }

        if (!more) break;
        // ---- rotate prefetched state ----
        pv = pvn; e0 = e0n; e1 = e1n; e2 = e2n; e3 = e3n;
        if (lane < 16) {
            #pragma unroll
            for (int j = 0; j < 12; ++j) cc[j] = ccn[j];
        }
        chunk = next;
    }
#undef DENSE_LAYER
}

extern "C" void kernel_launch(void* const* d_in, const int* in_sizes, int n_in,
                              void* d_out, int out_size, void* d_ws, size_t ws_size,
                              hipStream_t stream) {
    const float* coords  = (const float*)d_in[0];
    const int*   propers = (const int*)d_in[1];
    const float* encoded = (const float*)d_in[2];
    const float* tvec    = (const float*)d_in[3];
    const float* answer  = (const float*)d_in[4];
    const float* W0 = (const float*)d_in[5];
    const float* b0 = (const float*)d_in[6];
    const float* W1 = (const float*)d_in[7];
    const float* b1 = (const float*)d_in[8];
    const float* W2 = (const float*)d_in[9];
    const float* b2 = (const float*)d_in[10];
    const float* W3 = (const float*)d_in[11];
    const float* b3 = (const float*)d_in[12];
    float* out = (float*)d_out;
    char* ws = (char*)d_ws;
    bf16* W0sw = (bf16*)(ws + OFF_W0SW);
    bf16* W1sw = (bf16*)(ws + OFF_W1SW);
    bf16* W2sw = (bf16*)(ws + OFF_W2SW);
    bf16* W3sw = (bf16*)(ws + OFF_W3SW);
    bf16* WtB  = (bf16*)(ws + OFF_WTB);
    bf16* W5B  = (bf16*)(ws + OFF_W5B);
    bf16* E    = (bf16*)(ws + OFF_E);

    int prep_blocks = (PR_TOTAL + 255) / 256;
    prep_kernel<<<prep_blocks, 256, 0, stream>>>(W0, W1, W2, W3, answer, tvec, b0,
                                                 W0sw, W1sw, W2sw, W3sw, WtB, W5B, out);
    prep_e_kernel<<<391 * 4, 256, 0, stream>>>(encoded, W0sw, E);
    main_kernel<<<256, 512, 0, stream>>>(coords, propers, b1, b2, b3,
                                         E, W1sw, W2sw, W3sw, WtB, W5B, out);
}